// Round 11
// baseline (866.564 us; speedup 1.0000x reference)
//
#include <hip/hip_runtime.h>
#include <cmath>

#define S_   2048
#define B_   2
#define D_   1024
#define H_   16
#define DH_  64
#define DFF_ 4096
#define E_   4
#define T_   4096
#define SCALE_ 0.125f

typedef __attribute__((ext_vector_type(8))) short short8;
typedef __attribute__((ext_vector_type(4))) float f32x4;
typedef __attribute__((ext_vector_type(4))) unsigned short u16x4;
typedef __attribute__((ext_vector_type(4))) unsigned int u32x4;

static __device__ __forceinline__ unsigned short f2bf(float f) {
  union { float f; unsigned int u; } v; v.f = f;
  unsigned int r = v.u + 0x7FFFu + ((v.u >> 16) & 1u);
  return (unsigned short)(r >> 16);
}

static __device__ __forceinline__ float bf2f(unsigned short u) {
  union { unsigned int u; float f; } v; v.u = (unsigned int)u << 16;
  return v.f;
}

static __device__ __forceinline__ f32x4 mfma16(short8 a, short8 b, f32x4 c) {
  return __builtin_amdgcn_mfma_f32_16x16x32_bf16(a, b, c, 0, 0, 0);
}

// async global->LDS: 16B per lane; LDS dest = wave-uniform base + lane*16.
static __device__ __forceinline__ void gll16(const unsigned short* g, unsigned short* l) {
  __builtin_amdgcn_global_load_lds(
      (const __attribute__((address_space(1))) void*)g,
      (__attribute__((address_space(3))) void*)l, 16, 0, 0);
}

// fast gelu: vv * e^(2u) / (e^(2u)+1), u = 0.797885*(v+0.044715 v^3); max err ~3e-4
static __device__ __forceinline__ float gelu_f(float vv) {
  float u = 0.7978845608f * (vv + 0.044715f * vv * vv * vv);
  u = fminf(fmaxf(u, -9.0f), 9.0f);
  float e2 = __expf(2.0f * u);
  return vv * e2 * (1.0f / (e2 + 1.0f));
}

// ---------------- transpose + fp32->bf16: out[c][r] = bf16(in[r][c]), z-batched ------
__global__ void transpose_cvt(const float* __restrict__ in, unsigned short* __restrict__ out,
                              int R, int C) {
  __shared__ float t[64][33];
  size_t boff = (size_t)blockIdx.z * R * C;
  in += boff; out += boff;
  int c0 = blockIdx.x * 32, r0 = blockIdx.y * 64;
  for (int i = threadIdx.y; i < 64; i += 8)
    t[i][threadIdx.x] = in[(size_t)(r0 + i) * C + c0 + threadIdx.x];
  __syncthreads();
  for (int i = threadIdx.y; i < 32; i += 8) {
    float v0 = t[2 * threadIdx.x][i], v1 = t[2 * threadIdx.x + 1][i];
    unsigned int pk = (unsigned int)f2bf(v0) | ((unsigned int)f2bf(v1) << 16);
    *(unsigned int*)(&out[(size_t)(c0 + i) * R + r0 + 2 * threadIdx.x]) = pk;
  }
}

__global__ void transpose_cvt_split(const float* __restrict__ in,
    unsigned short* __restrict__ outh, unsigned short* __restrict__ outl, int R, int C) {
  __shared__ float t[64][33];
  int c0 = blockIdx.x * 32, r0 = blockIdx.y * 64;
  for (int i = threadIdx.y; i < 64; i += 8)
    t[i][threadIdx.x] = in[(size_t)(r0 + i) * C + c0 + threadIdx.x];
  __syncthreads();
  for (int i = threadIdx.y; i < 32; i += 8) {
    float v0 = t[2 * threadIdx.x][i], v1 = t[2 * threadIdx.x + 1][i];
    unsigned short h0 = f2bf(v0), h1 = f2bf(v1);
    unsigned int hp = (unsigned int)h0 | ((unsigned int)h1 << 16);
    unsigned int lp = (unsigned int)f2bf(v0 - bf2f(h0)) |
                      ((unsigned int)f2bf(v1 - bf2f(h1)) << 16);
    size_t o = (size_t)(c0 + i) * R + r0 + 2 * threadIdx.x;
    *(unsigned int*)(&outh[o]) = hp;
    *(unsigned int*)(&outl[o]) = lp;
  }
}

// ---------------- V transpose: kv[(j*B+b)][n*128+64+d] -> vT[((b*16+n)*64+d)][j] ------
__global__ __launch_bounds__(256) void v_transpose(
    const unsigned short* __restrict__ kvh, const unsigned short* __restrict__ kvl,
    unsigned short* __restrict__ vTh, unsigned short* __restrict__ vTl) {
  __shared__ unsigned short th[64][72], tl[64][72];
  int j0 = blockIdx.x * 64;
  int bh = blockIdx.y;
  int b = bh & 1, n = bh >> 1;
  int tid = threadIdx.x;
  int jr = tid >> 3, dc = (tid & 7) * 8;
  for (int it = 0; it < 2; ++it) {
    int jj = it * 32 + jr;
    size_t src = ((size_t)((j0 + jj) * 2 + b)) * 2048 + n * 128 + 64 + dc;
    *(short8*)(&th[jj][dc]) = *(const short8*)(kvh + src);
    *(short8*)(&tl[jj][dc]) = *(const short8*)(kvl + src);
  }
  __syncthreads();
  int dr = tid >> 3, jc = (tid & 7) * 8;
  for (int it = 0; it < 2; ++it) {
    int d = it * 32 + dr;
    short8 oh, ol;
    for (int u = 0; u < 8; ++u) { oh[u] = th[jc + u][d]; ol[u] = tl[jc + u][d]; }
    size_t dst = ((size_t)((b * 16 + n) * 64 + d)) * 2048 + j0 + jc;
    *(short8*)(vTh + dst) = oh;
    *(short8*)(vTl + dst) = ol;
  }
}

// ---------------- block reduce (sum, sumsq) over 256 threads -------------------------
static __device__ __forceinline__ void block_reduce2(float& s, float& s2, float* sh) {
  __syncthreads();
  for (int off = 32; off; off >>= 1) { s += __shfl_down(s, off); s2 += __shfl_down(s2, off); }
  int w = threadIdx.x >> 6;
  if ((threadIdx.x & 63) == 0) { sh[w * 2] = s; sh[w * 2 + 1] = s2; }
  __syncthreads();
  s = sh[0] + sh[2] + sh[4] + sh[6];
  s2 = sh[1] + sh[3] + sh[5] + sh[7];
}

// ---------------- input layernorm: h (f32) + split bf16 ------------------------------
__global__ __launch_bounds__(256) void ln_in_kernel(const float* __restrict__ hid,
    const float* __restrict__ g, const float* __restrict__ b,
    float* __restrict__ h, unsigned short* __restrict__ hbh, unsigned short* __restrict__ hbl) {
  __shared__ float sh[8];
  int t = blockIdx.x, tid = threadIdx.x;
  size_t ro = (size_t)t * D_;
  f32x4 v = ((const f32x4*)(hid + ro))[tid];
  float s = v[0] + v[1] + v[2] + v[3];
  float s2 = v[0]*v[0] + v[1]*v[1] + v[2]*v[2] + v[3]*v[3];
  block_reduce2(s, s2, sh);
  float mean = s * (1.0f / D_);
  float var = s2 * (1.0f / D_) - mean * mean;
  float rstd = rsqrtf(var + 1e-6f);
  f32x4 gv = ((const f32x4*)g)[tid], bv = ((const f32x4*)b)[tid];
  f32x4 y; u16x4 yh, yl;
  for (int c = 0; c < 4; ++c) {
    float z = (v[c] - mean) * rstd * gv[c] + bv[c];
    y[c] = z; yh[c] = f2bf(z); yl[c] = f2bf(z - bf2f(yh[c]));
  }
  ((f32x4*)(h + ro))[tid] = y;
  ((u16x4*)(hbh + ro))[tid] = yh;
  ((u16x4*)(hbl + ro))[tid] = yl;
}

// ---------------- fused: attn-LN + residual + post-LN --------------------------------
__global__ __launch_bounds__(256) void ln_fused_kernel(
    const float* __restrict__ hid, const float* __restrict__ h, const float* __restrict__ ao,
    const float* __restrict__ ga, const float* __restrict__ ba,
    const float* __restrict__ gp, const float* __restrict__ bp,
    float* __restrict__ out, float* __restrict__ x, unsigned short* __restrict__ xb) {
  __shared__ float sh[8];
  int t = blockIdx.x, tid = threadIdx.x;
  size_t ro = (size_t)t * D_;
  f32x4 hv = ((const f32x4*)(h + ro))[tid];
  f32x4 av = ((const f32x4*)(ao + ro))[tid];
  f32x4 a = hv + av;
  float s = a[0] + a[1] + a[2] + a[3];
  float s2 = a[0]*a[0] + a[1]*a[1] + a[2]*a[2] + a[3]*a[3];
  block_reduce2(s, s2, sh);
  float mean = s * (1.0f / D_);
  float var = s2 * (1.0f / D_) - mean * mean;
  float rstd = rsqrtf(var + 1e-5f);
  f32x4 lg = ((const f32x4*)ga)[tid], lb = ((const f32x4*)ba)[tid];
  f32x4 hidv = ((const f32x4*)(hid + ro))[tid];
  f32x4 li;
  for (int c = 0; c < 4; ++c) li[c] = hidv[c] + (a[c] - mean) * rstd * lg[c] + lb[c];
  ((f32x4*)(out + ro))[tid] = li;
  float s3 = li[0] + li[1] + li[2] + li[3];
  float s4 = li[0]*li[0] + li[1]*li[1] + li[2]*li[2] + li[3]*li[3];
  block_reduce2(s3, s4, sh);
  float mean2 = s3 * (1.0f / D_);
  float var2 = s4 * (1.0f / D_) - mean2 * mean2;
  float rstd2 = rsqrtf(var2 + 1e-6f);
  f32x4 g2 = ((const f32x4*)gp)[tid], b2v = ((const f32x4*)bp)[tid];
  f32x4 xv; u16x4 xbv;
  for (int c = 0; c < 4; ++c) { float z = (li[c] - mean2) * rstd2 * g2[c] + b2v[c]; xv[c] = z; xbv[c] = f2bf(z); }
  ((f32x4*)(x + ro))[tid] = xv;
  ((u16x4*)(xb + ro))[tid] = xbv;
}

// ---------------- fused Q+KV split-bf16 GEMM, T3 pipeline + chunk swizzle ------------
// Q outputs are pre-scaled by SCALE (exact pow2) so attn skips per-score scaling.
__global__ __launch_bounds__(256) void qkv_gemm(
    const unsigned short* __restrict__ Ah, const unsigned short* __restrict__ Al,
    const unsigned short* __restrict__ WqTh, const unsigned short* __restrict__ WqTl,
    const unsigned short* __restrict__ WkvTh, const unsigned short* __restrict__ WkvTl,
    unsigned short* __restrict__ qh, unsigned short* __restrict__ ql,
    unsigned short* __restrict__ kvh, unsigned short* __restrict__ kvl) {
  const int K = 1024;
  int m0 = blockIdx.y * 128, n0g = blockIdx.x * 128;
  const unsigned short *Bh, *Bl;
  unsigned short *Ch, *Cl;
  int NC, n0;
  float cscale;
  if (n0g < 1024) { Bh = WqTh; Bl = WqTl; Ch = qh; Cl = ql; NC = 1024; n0 = n0g; cscale = SCALE_; }
  else { Bh = WkvTh; Bl = WkvTl; Ch = kvh; Cl = kvl; NC = 2048; n0 = n0g - 1024; cscale = 1.0f; }
  __shared__ unsigned short pool2[32768];
  unsigned short* buf[2] = { pool2, pool2 + 16384 };
  int tid = threadIdx.x;
  int lane = tid & 63, w = tid >> 6;
  int quad = lane >> 4, l15 = lane & 15;
  int wm = (w >> 1) * 64, wn = (w & 1) * 64;
  f32x4 acc[4][4];
  for (int i = 0; i < 4; ++i) for (int j = 0; j < 4; ++j) acc[i][j] = 0;
  int rs0 = w * 32 + (lane >> 2), rs1 = rs0 + 16;
  int sw = ((lane & 3) ^ ((lane >> 3) & 3)) * 8;   // pre-swizzled source chunk
  const unsigned short* gah0 = Ah + (size_t)(m0 + rs0) * K + sw;
  const unsigned short* gah1 = Ah + (size_t)(m0 + rs1) * K + sw;
  const unsigned short* gal0 = Al + (size_t)(m0 + rs0) * K + sw;
  const unsigned short* gal1 = Al + (size_t)(m0 + rs1) * K + sw;
  const unsigned short* gbh0 = Bh + (size_t)(n0 + rs0) * K + sw;
  const unsigned short* gbh1 = Bh + (size_t)(n0 + rs1) * K + sw;
  const unsigned short* gbl0 = Bl + (size_t)(n0 + rs0) * K + sw;
  const unsigned short* gbl1 = Bl + (size_t)(n0 + rs1) * K + sw;
  int so0 = (w * 2 + 0) * 512, so1 = (w * 2 + 1) * 512;
  int sq = (l15 >> 1) & 3;                          // read-side swizzle
  auto stage = [&](unsigned short* bb, int k) {
    gll16(gah0 + k, bb + so0);         gll16(gah1 + k, bb + so1);
    gll16(gal0 + k, bb + 4096 + so0);  gll16(gal1 + k, bb + 4096 + so1);
    gll16(gbh0 + k, bb + 8192 + so0);  gll16(gbh1 + k, bb + 8192 + so1);
    gll16(gbl0 + k, bb + 12288 + so0); gll16(gbl1 + k, bb + 12288 + so1);
  };
  auto compute = [&](const unsigned short* bb) {
    short8 afh[4], afl[4], bfh[4], bfl[4];
    for (int i = 0; i < 4; ++i) {
      int o = (wm + i * 16 + l15) * 32 + ((quad ^ sq) * 8);
      afh[i] = *(const short8*)(&bb[o]);
      afl[i] = *(const short8*)(&bb[4096 + o]);
    }
    for (int j = 0; j < 4; ++j) {
      int o = (wn + j * 16 + l15) * 32 + ((quad ^ sq) * 8);
      bfh[j] = *(const short8*)(&bb[8192 + o]);
      bfl[j] = *(const short8*)(&bb[12288 + o]);
    }
    for (int i = 0; i < 4; ++i)
      for (int j = 0; j < 4; ++j) {
        f32x4 a = acc[i][j];
        a = mfma16(afh[i], bfl[j], a);
        a = mfma16(afl[i], bfh[j], a);
        a = mfma16(afh[i], bfh[j], a);
        acc[i][j] = a;
      }
  };
  stage(buf[0], 0);
  __syncthreads();
  for (int k0 = 0; k0 < K; k0 += 64) {
    stage(buf[1], k0 + 32);
    compute(buf[0]);
    __syncthreads();
    if (k0 + 64 < K) stage(buf[0], k0 + 64);
    compute(buf[1]);
    __syncthreads();
  }
  // coalesced epilogue through LDS
  unsigned short* eph = &pool2[w * 1152];
  unsigned short* epl = &pool2[4608 + w * 1152];
  int row16 = lane >> 3, chunk = lane & 7;
  for (int i = 0; i < 4; ++i) {
    for (int j = 0; j < 4; ++j) {
      f32x4 a = acc[i][j];
      int lo = j * 16 + l15;
      for (int r = 0; r < 4; ++r) {
        float av = a[r] * cscale;
        unsigned short hb = f2bf(av);
        eph[(quad * 4 + r) * 72 + lo] = hb;
        epl[(quad * 4 + r) * 72 + lo] = f2bf(av - bf2f(hb));
      }
    }
    for (int it = 0; it < 2; ++it) {
      int rr = it * 8 + row16;
      size_t go = (size_t)(m0 + wm + i * 16 + rr) * NC + n0 + wn + chunk * 8;
      *(u32x4*)(&Ch[go]) = *(const u32x4*)(&eph[rr * 72 + chunk * 8]);
      *(u32x4*)(&Cl[go]) = *(const u32x4*)(&epl[rr * 72 + chunk * 8]);
    }
    __syncthreads();
  }
}

// ---------------- split-bf16 GEMM, MT x 128 tile, f32 output (Wo) --------------------
template<int MT>
__global__ __launch_bounds__(256) void gemm3f(
    const unsigned short* __restrict__ Ah, const unsigned short* __restrict__ Al,
    const unsigned short* __restrict__ Bh, const unsigned short* __restrict__ Bl,
    float* __restrict__ Cf, int N, int K) {
  int m0 = blockIdx.y * MT, n0 = blockIdx.x * 128;
  __shared__ unsigned short pool3[MT * 64 + 8192];
  unsigned short* Ash = pool3;
  unsigned short* Asl = pool3 + MT * 32;
  unsigned short* Bsh = pool3 + MT * 64;
  unsigned short* Bsl = pool3 + MT * 64 + 4096;
  int tid = threadIdx.x;
  int lane = tid & 63, w = tid >> 6;
  int quad = lane >> 4, l15 = lane & 15;
  int wm = (w >> 1) * (MT / 2), wn = (w & 1) * 64;
  constexpr int MI = MT / 32;
  f32x4 acc[MI][4];
  for (int i = 0; i < MI; ++i) for (int j = 0; j < 4; ++j) acc[i][j] = 0;
  constexpr int AI = MT / 64;  // A issues per wave
  int cofs = (lane & 3) * 8;
  const unsigned short* gah[AI]; const unsigned short* gal[AI];
  unsigned short *lAh[AI], *lAl[AI];
  for (int is = 0; is < AI; ++is) {
    int rs = w * (MT / 4) + is * 16 + (lane >> 2);
    gah[is] = Ah + (size_t)(m0 + rs) * K + cofs;
    gal[is] = Al + (size_t)(m0 + rs) * K + cofs;
    lAh[is] = &Ash[(w * AI + is) * 512];
    lAl[is] = &Asl[(w * AI + is) * 512];
  }
  int rsB0 = w * 32 + (lane >> 2), rsB1 = rsB0 + 16;
  const unsigned short* gbh0 = Bh + (size_t)(n0 + rsB0) * K + cofs;
  const unsigned short* gbh1 = Bh + (size_t)(n0 + rsB1) * K + cofs;
  const unsigned short* gbl0 = Bl + (size_t)(n0 + rsB0) * K + cofs;
  const unsigned short* gbl1 = Bl + (size_t)(n0 + rsB1) * K + cofs;
  unsigned short* lB0 = &Bsh[(w * 2 + 0) * 512];
  unsigned short* lB1 = &Bsh[(w * 2 + 1) * 512];
  unsigned short* lBl0 = &Bsl[(w * 2 + 0) * 512];
  unsigned short* lBl1 = &Bsl[(w * 2 + 1) * 512];
  for (int k0 = 0; k0 < K; k0 += 32) {
    __syncthreads();
    for (int is = 0; is < AI; ++is) { gll16(gah[is] + k0, lAh[is]); gll16(gal[is] + k0, lAl[is]); }
    gll16(gbh0 + k0, lB0); gll16(gbh1 + k0, lB1);
    gll16(gbl0 + k0, lBl0); gll16(gbl1 + k0, lBl1);
    __syncthreads();
    short8 afh[MI], afl[MI], bfh[4], bfl[4];
    for (int i = 0; i < MI; ++i) {
      int o = (wm + i * 16 + l15) * 32 + quad * 8;
      afh[i] = *(const short8*)(&Ash[o]);
      afl[i] = *(const short8*)(&Asl[o]);
    }
    for (int j = 0; j < 4; ++j) {
      int o = (wn + j * 16 + l15) * 32 + quad * 8;
      bfh[j] = *(const short8*)(&Bsh[o]);
      bfl[j] = *(const short8*)(&Bsl[o]);
    }
    for (int i = 0; i < MI; ++i)
      for (int j = 0; j < 4; ++j) {
        f32x4 a = acc[i][j];
        a = mfma16(afh[i], bfl[j], a);
        a = mfma16(afl[i], bfh[j], a);
        a = mfma16(afh[i], bfh[j], a);
        acc[i][j] = a;
      }
  }
  // coalesced f32 epilogue through LDS: per-wave 16x64 f32 slab (stride 68)
  __syncthreads();
  float* epf = (float*)(pool3 + w * 2176);
  for (int i = 0; i < MI; ++i) {
    for (int j = 0; j < 4; ++j) {
      f32x4 a = acc[i][j];
      for (int r = 0; r < 4; ++r) epf[(quad * 4 + r) * 68 + j * 16 + l15] = a[r];
    }
    for (int it = 0; it < 4; ++it) {
      int rr = (lane >> 4) + it * 4;
      int ch = lane & 15;
      *(f32x4*)(&Cf[(size_t)(m0 + wm + i * 16 + rr) * N + n0 + wn + ch * 4]) =
          *(const f32x4*)(&epf[rr * 68 + ch * 4]);
    }
    __syncthreads();
  }
}

// ---------------- MoE up, T3 pipeline + bank-conflict-free chunk swizzle -------------
__global__ __launch_bounds__(256) void moe_up(
    const unsigned short* __restrict__ A, const unsigned short* __restrict__ W1T,
    unsigned short* __restrict__ hmid, int N, int K,
    const int* __restrict__ cnt, const int* __restrict__ offs,
    const int* __restrict__ list, const float* __restrict__ b1) {
  int e = blockIdx.y >> 5, mt = blockIdx.y & 31;
  int M = cnt[e];
  int m0 = mt * 128, n0 = blockIdx.x * 128;
  if (M == 0 || m0 >= M) return;
  const unsigned short* Bt = W1T + (size_t)e * DFF_ * D_;
  const int* liste = list + e * T_;
  const float* bias = b1 + (size_t)e * DFF_;
  size_t obase = (size_t)offs[e];
  __shared__ unsigned short pool[16384];
  unsigned short* As0 = pool;
  unsigned short* Bs0 = pool + 4096;
  unsigned short* As1 = pool + 8192;
  unsigned short* Bs1 = pool + 12288;
  int tid = threadIdx.x;
  int lane = tid & 63, w = tid >> 6;
  int quad = lane >> 4, l15 = lane & 15;
  int wm = (w >> 1) * 64, wn = (w & 1) * 64;
  f32x4 acc[4][4];
  for (int i = 0; i < 4; ++i) for (int j = 0; j < 4; ++j) acc[i][j] = 0;
  int rs0 = w * 32 + (lane >> 2), rs1 = rs0 + 16;
  int sw = ((lane & 3) ^ ((lane >> 3) & 3)) * 8;    // pre-swizzled source chunk
  const unsigned short* ga0 = A + (size_t)liste[min(m0 + rs0, M - 1)] * K + sw;
  const unsigned short* ga1 = A + (size_t)liste[min(m0 + rs1, M - 1)] * K + sw;
  const unsigned short* gb0 = Bt + (size_t)(n0 + rs0) * K + sw;
  const unsigned short* gb1 = Bt + (size_t)(n0 + rs1) * K + sw;
  int so0 = (w * 2 + 0) * 512, so1 = (w * 2 + 1) * 512;
  int sq = (l15 >> 1) & 3;                           // read-side swizzle
  auto stage = [&](unsigned short* Ab, unsigned short* Bb, int k) {
    gll16(ga0 + k, Ab + so0); gll16(ga1 + k, Ab + so1);
    gll16(gb0 + k, Bb + so0); gll16(gb1 + k, Bb + so1);
  };
  auto compute = [&](const unsigned short* Ab, const unsigned short* Bb) {
    short8 af[4], bfr[4];
    for (int i = 0; i < 4; ++i)
      af[i] = *(const short8*)(&Ab[(wm + i * 16 + l15) * 32 + (quad ^ sq) * 8]);
    for (int j = 0; j < 4; ++j)
      bfr[j] = *(const short8*)(&Bb[(wn + j * 16 + l15) * 32 + (quad ^ sq) * 8]);
    for (int i = 0; i < 4; ++i)
      for (int j = 0; j < 4; ++j)
        acc[i][j] = mfma16(af[i], bfr[j], acc[i][j]);
  };
  stage(As0, Bs0, 0);
  __syncthreads();
  for (int k0 = 0; k0 < K; k0 += 64) {
    stage(As1, Bs1, k0 + 32);
    compute(As0, Bs0);
    __syncthreads();
    if (k0 + 64 < K) stage(As0, Bs0, k0 + 64);
    compute(As1, Bs1);
    __syncthreads();
  }
  // coalesced epilogue through LDS: per-wave 16x64 slab, stride 72
  unsigned short* ep = &pool[w * 1152];
  int row16 = lane >> 3, chunk = lane & 7;
  for (int i = 0; i < 4; ++i) {
    for (int j = 0; j < 4; ++j) {
      f32x4 a = acc[i][j];
      int colg = n0 + wn + j * 16 + l15;
      float bv = bias[colg];
      for (int r = 0; r < 4; ++r)
        ep[(quad * 4 + r) * 72 + j * 16 + l15] = f2bf(gelu_f(a[r] + bv));
    }
    for (int it = 0; it < 2; ++it) {
      int rr = it * 8 + row16;
      int rowg = m0 + wm + i * 16 + rr;
      if (rowg < M)
        *(u32x4*)(&hmid[(obase + rowg) * DFF_ + n0 + wn + chunk * 8]) =
            *(const u32x4*)(&ep[rr * 72 + chunk * 8]);
    }
  }
}

// ---------------- MoE down, 128x128 tile, split-K=2, T3 pipeline + chunk swizzle -----
// grid (D/128, E*32, 2): z = K-half. Output via atomicAdd; bias added only by z==0.
__global__ __launch_bounds__(256) void moe_down(
    const unsigned short* __restrict__ hmid, const unsigned short* __restrict__ W2T,
    int N, int K,
    const int* __restrict__ cnt, const int* __restrict__ offs,
    const int* __restrict__ list, const float* __restrict__ gatev,
    const float* __restrict__ b2, float* __restrict__ accum) {
  int e = blockIdx.y >> 5, mt = blockIdx.y & 31;
  int M = cnt[e];
  int m0 = mt * 128, n0 = blockIdx.x * 128;
  if (M == 0 || m0 >= M) return;
  int kbeg = blockIdx.z * (K >> 1);
  int kend = kbeg + (K >> 1);
  const unsigned short* A = hmid + (size_t)offs[e] * DFF_;
  const unsigned short* Bt = W2T + (size_t)e * D_ * DFF_;
  const int* liste = list + e * T_;
  const float* gv = gatev + e * T_;
  const float* bias = b2 + (size_t)e * D_;
  __shared__ unsigned short pool[16384];
  unsigned short* As0 = pool;
  unsigned short* Bs0 = pool + 4096;
  unsigned short* As1 = pool + 8192;
  unsigned short* Bs1 = pool + 12288;
  int tid = threadIdx.x;
  int lane = tid & 63, w = tid >> 6;
  int quad = lane >> 4, l15 = lane & 15;
  int wm = (w >> 1) * 64, wn = (w & 1) * 64;
  f32x4 acc[4][4];
  for (int i = 0; i < 4; ++i) for (int j = 0; j < 4; ++j) acc[i][j] = 0;
  int rs0 = w * 32 + (lane >> 2), rs1 = rs0 + 16;
  int sw = ((lane & 3) ^ ((lane >> 3) & 3)) * 8;
  const unsigned short* ga0 = A + (size_t)min(m0 + rs0, M - 1) * K + sw;
  const unsigned short* ga1 = A + (size_t)min(m0 + rs1, M - 1) * K + sw;
  const unsigned short* gb0 = Bt + (size_t)(n0 + rs0) * K + sw;
  const unsigned short* gb1 = Bt + (size_t)(n0 + rs1) * K + sw;
  int so0 = (w * 2 + 0) * 512, so1 = (w * 2 + 1) * 512;
  int sq = (l15 >> 1) & 3;
  auto stage = [&](unsigned short* Ab, unsigned short* Bb, int k) {
    gll16(ga0 + k, Ab + so0); gll16(ga1 + k, Ab + so1);
    gll16(gb0 + k, Bb + so0); gll16(gb1 + k, Bb + so1);
  };
  auto compute = [&](const unsigned short* Ab, const unsigned short* Bb) {
    short8 af[4], bfr[4];
    for (int i = 0; i < 4; ++i)
      af[i] = *(const short8*)(&Ab[(wm + i * 16 + l15) * 32 + (quad ^ sq) * 8]);
    for (int j = 0; j < 4; ++j)
      bfr[j] = *(const short8*)(&Bb[(wn + j * 16 + l15) * 32 + (quad ^ sq) * 8]);
    for (int i = 0; i < 4; ++i)
      for (int j = 0; j < 4; ++j)
        acc[i][j] = mfma16(af[i], bfr[j], acc[i][j]);
  };
  stage(As0, Bs0, kbeg);
  __syncthreads();
  for (int k0 = kbeg; k0 < kend; k0 += 64) {
    stage(As1, Bs1, k0 + 32);
    compute(As0, Bs0);
    __syncthreads();
    if (k0 + 64 < kend) stage(As0, Bs0, k0 + 64);
    compute(As1, Bs1);
    __syncthreads();
  }
  float bsc = (blockIdx.z == 0) ? 1.0f : 0.0f;
  for (int i = 0; i < 4; ++i) for (int j = 0; j < 4; ++j) {
    int row = m0 + wm + i * 16 + quad * 4;
    int col = n0 + wn + j * 16 + l15;
    f32x4 a = acc[i][j];
    float bv = bias[col] * bsc;
    for (int r = 0; r < 4; ++r) if (row + r < M) {
      int tt = liste[row + r];
      float gg = gv[row + r];
      atomicAdd(&accum[(size_t)tt * D_ + col], gg * (a[r] + bv));
    }
  }
}

// ---------------- flash attention: shared LDS K+V, T3 pipeline, lean softmax ---------
// Q pre-scaled by SCALE in qkv_gemm. Defer-max (THR=8, exact when skipped) +
// per-lane partial l (reduced once at end).
__global__ __launch_bounds__(256, 2) void attn_kernel(
    const unsigned short* __restrict__ qh, const unsigned short* __restrict__ ql,
    const unsigned short* __restrict__ kvh, const unsigned short* __restrict__ kvl,
    const unsigned short* __restrict__ vTh, const unsigned short* __restrict__ vTl,
    unsigned short* __restrict__ avh, unsigned short* __restrict__ avl) {
  int bh = blockIdx.x;     // x = bh so all q-tiles of one (b,head) share an XCD (bh%8)
  int itile = blockIdx.y;
  int b = bh & 1, n = bh >> 1;
  __shared__ unsigned short Kh[2][4096], Kl[2][4096], Vh[2][4096], Vl[2][4096];
  __shared__ unsigned short Ps[4][1152];
  int tid = threadIdx.x;
  int w = tid >> 6, lane = tid & 63, quad = lane >> 4, l15 = lane & 15;
  int i_base = itile * 64 + w * 16;
  short8 qfh[2], qfl[2];
  {
    size_t qo = ((size_t)((i_base + l15) * B_ + b)) * 1024 + n * 64;
    qfh[0] = *(const short8*)(qh + qo + quad * 8);
    qfh[1] = *(const short8*)(qh + qo + 32 + quad * 8);
    qfl[0] = *(const short8*)(ql + qo + quad * 8);
    qfl[1] = *(const short8*)(ql + qo + 32 + quad * 8);
  }
  float m_i[4], lp[4];
  f32x4 o[4];
  for (int r = 0; r < 4; ++r) { m_i[r] = -1e30f; lp[r] = 0.0f; }
  for (int d = 0; d < 4; ++d) o[d] = 0;
  // staging: thread t covers tile rows jk and jk+32 with swizzled chunk ck
  int jk = tid >> 3;
  int ck = (tid & 7) ^ (jk & 7);
  size_t kS = ((size_t)(jk * 2 + b)) * 2048 + (size_t)n * 128 + ck * 8;   // +jt*262144; +131072 upper
  size_t vS = ((size_t)((b * 16 + n) * 64 + jk)) * 2048 + ck * 8;         // +jt*64; +65536 upper
  int ldst = tid * 8;
  unsigned short* psw = &Ps[w][0];
  // prologue: stage tile 0 into buffer 0
  gll16(kvh + kS, &Kh[0][ldst]);           gll16(kvh + kS + 131072, &Kh[0][2048 + ldst]);
  gll16(kvl + kS, &Kl[0][ldst]);           gll16(kvl + kS + 131072, &Kl[0][2048 + ldst]);
  gll16(vTh + vS, &Vh[0][ldst]);           gll16(vTh + vS + 65536, &Vh[0][2048 + ldst]);
  gll16(vTl + vS, &Vl[0][ldst]);           gll16(vTl + vS + 65536, &Vl[0][2048 + ldst]);
  __syncthreads();
  for (int jt = 0; jt < 32; ++jt) {
    int cur = jt & 1;
    if (jt < 31) {   // stage next tile into other buffer; lands by loop-end barrier
      int nb = cur ^ 1;
      size_t ks2 = kS + (size_t)(jt + 1) * 262144;
      size_t vs2 = vS + (size_t)(jt + 1) * 64;
      gll16(kvh + ks2, &Kh[nb][ldst]);     gll16(kvh + ks2 + 131072, &Kh[nb][2048 + ldst]);
      gll16(kvl + ks2, &Kl[nb][ldst]);     gll16(kvl + ks2 + 131072, &Kl[nb][2048 + ldst]);
      gll16(vTh + vs2, &Vh[nb][ldst]);     gll16(vTh + vs2 + 65536, &Vh[nb][2048 + ldst]);
      gll16(vTl + vs2, &Vl[nb][ldst]);     gll16(vTl + vs2 + 65536, &Vl[nb][2048 + ldst]);
    }
    // QK^T from swizzled LDS (scores already scaled: Q pre-scaled by SCALE)
    f32x4 sac[4];
    __builtin_amdgcn_s_setprio(1);
    for (int t4 = 0; t4 < 4; ++t4) {
      int j = t4 * 16 + l15;
      int base = j * 64;
      int c0 = (quad ^ (j & 7)) << 3;
      int c1 = ((quad | 4) ^ (j & 7)) << 3;
      short8 kh0 = *(const short8*)(&Kh[cur][base + c0]);
      short8 kh1 = *(const short8*)(&Kh[cur][base + c1]);
      short8 kl0 = *(const short8*)(&Kl[cur][base + c0]);
      short8 kl1 = *(const short8*)(&Kl[cur][base + c1]);
      f32x4 a = 0;
      a = mfma16(qfh[0], kl0, a);
      a = mfma16(qfh[1], kl1, a);
      a = mfma16(qfl[0], kh0, a);
      a = mfma16(qfl[1], kh1, a);
      a = mfma16(qfh[0], kh0, a);
      a = mfma16(qfh[1], kh1, a);
      sac[t4] = a;
    }
    __builtin_amdgcn_s_setprio(0);
    // lean online softmax: defer-max (THR=8) + per-lane partial l
    float m1[4];
    for (int r = 0; r < 4; ++r) {
      float v = fmaxf(fmaxf(sac[0][r], sac[1][r]), fmaxf(sac[2][r], sac[3][r]));
      for (int off = 1; off < 16; off <<= 1) v = fmaxf(v, __shfl_xor(v, off, 16));
      m1[r] = v;
    }
    float p[4][4];
    bool ok = (m1[0] <= m_i[0] + 8.f) && (m1[1] <= m_i[1] + 8.f) &&
              (m1[2] <= m_i[2] + 8.f) && (m1[3] <= m_i[3] + 8.f);
    if (__all(ok)) {
      for (int r = 0; r < 4; ++r) {
        float rs = 0.f;
        for (int t4 = 0; t4 < 4; ++t4) {
          float pp = __expf(sac[t4][r] - m_i[r]);
          p[t4][r] = pp; rs += pp;
        }
        lp[r] += rs;
      }
    } else {
      float alpha[4];
      for (int r = 0; r < 4; ++r) {
        float mnew = fmaxf(m_i[r], m1[r]);
        alpha[r] = __expf(m_i[r] - mnew);
        m_i[r] = mnew;
        float rs = 0.f;
        for (int t4 = 0; t4 < 4; ++t4) {
          float pp = __expf(sac[t4][r] - mnew);
          p[t4][r] = pp; rs += pp;
        }
        lp[r] = lp[r] * alpha[r] + rs;
      }
      for (int d = 0; d < 4; ++d) for (int r = 0; r < 4; ++r) o[d][r] *= alpha[r];
    }
    // restage P (high only) into wave-private slab; compiler lgkmcnt orders PV reads
    for (int t4 = 0; t4 < 4; ++t4) for (int r = 0; r < 4; ++r)
      psw[(quad * 4 + r) * 72 + t4 * 16 + l15] = f2bf(p[t4][r]);
    // PV from swizzled LDS V
    __builtin_amdgcn_s_setprio(1);
    for (int dblk = 0; dblk < 4; ++dblk) {
      f32x4 a = o[dblk];
      int d = dblk * 16 + l15;
      int vb = d * 64;
      for (int ks = 0; ks < 2; ++ks) {
        short8 pfh = *(const short8*)(&psw[l15 * 72 + ks * 32 + quad * 8]);
        int ch = ((ks * 4 + quad) ^ (d & 7)) << 3;
        short8 vfh = *(const short8*)(&Vh[cur][vb + ch]);
        short8 vfl = *(const short8*)(&Vl[cur][vb + ch]);
        a = mfma16(pfh, vfl, a);
        a = mfma16(pfh, vfh, a);
      }
      o[dblk] = a;
    }
    __builtin_amdgcn_s_setprio(0);
    __syncthreads();   // drains vmcnt: next tile staged; buffers safe to swap
  }
  // final l reduce (once) + coalesced epilogue through wave-private slab
  float l_i[4];
  for (int r = 0; r < 4; ++r) {
    float v = lp[r];
    for (int off = 1; off < 16; off <<= 1) v += __shfl_xor(v, off, 16);
    l_i[r] = v;
  }
  {
    int row16 = lane >> 3, chunk = lane & 7;
    for (int d = 0; d < 4; ++d) for (int r = 0; r < 4; ++r) {
      float val = o[d][r] / l_i[r];
      psw[(quad * 4 + r) * 72 + d * 16 + l15] = f2bf(val);
    }
    for (int it = 0; it < 2; ++it) {
      int rr = it * 8 + row16;
      size_t go = ((size_t)((i_base + rr) * B_ + b)) * 1024 + n * 64 + chunk * 8;
      *(u32x4*)(&avh[go]) = *(const u32x4*)(&psw[rr * 72 + chunk * 8]);
    }
    __syncthreads();
    for (int d = 0; d < 4; ++d) for (int r = 0; r < 4; ++r) {
      float val = o[d][r] / l_i[r];
      unsigned short hb = f2bf(val);
      psw[(quad * 4 + r) * 72 + d * 16 + l15] = f2bf(val - bf2f(hb));
    }
    for (int it = 0; it < 2; ++it) {
      int rr = it * 8 + row16;
      size_t go = ((size_t)((i_base + rr) * B_ + b)) * 1024 + n * 64 + chunk * 8;
      *(u32x4*)(&avl[go]) = *(const u32x4*)(&psw[rr * 72 + chunk * 8]);
    }
  }
}

// ---------------- gating v2: 64 tokens/block, ballot-based list build ----------------
__global__ __launch_bounds__(256) void gate_kernel(const float* __restrict__ x,
    const float* __restrict__ Wg, int* __restrict__ cnt,
    float* __restrict__ me_sum, float* __restrict__ ce_sum,
    int* __restrict__ list, float* __restrict__ gatev) {
  __shared__ float sl[64][4];
  int w = threadIdx.x >> 6, lane = threadIdx.x & 63;
  int tbase = blockIdx.x * 64;
  // Phase A: logits for 64 tokens (16 per wave, full-wave dot each)
  for (int k = 0; k < 16; ++k) {
    int t = tbase + w * 16 + k;
    f32x4 acc = 0;
    const float* xr = x + (size_t)t * D_;
    for (int j = 0; j < 16; ++j) {
      int d = j * 64 + lane;
      float xd = xr[d];
      f32x4 wg = ((const f32x4*)Wg)[d];
      acc += xd * wg;
    }
    for (int c = 0; c < 4; ++c) {
      float vv = acc[c];
      for (int off = 32; off; off >>= 1) vv += __shfl_down(vv, off);
      if (lane == 0) sl[w * 16 + k][c] = vv;
    }
  }
  __syncthreads();
  // Phase B: wave 0 only; one token per lane
  if (w == 0) {
    int t = tbase + lane;
    float p[4];
    float mx = fmaxf(fmaxf(sl[lane][0], sl[lane][1]), fmaxf(sl[lane][2], sl[lane][3]));
    float sum = 0.f;
    for (int e = 0; e < 4; ++e) { p[e] = expf(sl[lane][e] - mx); sum += p[e]; }
    float inv = 1.0f / sum;
    for (int e = 0; e < 4; ++e) p[e] *= inv;
    int i0 = 0;
    for (int e = 1; e < 4; ++e) if (p[e] > p[i0]) i0 = e;
    int i1 = (i0 == 0) ? 1 : 0;
    for (int e = 0; e < 4; ++e) if (e != i0 && p[e] > p[i1]) i1 = e;
    float g0 = p[i0] / (p[i0] + p[i1]);
    float g1 = p[i1] / (p[i0] + p[i1]);
    // me_sum: block-reduce probs, 4 atomics
    for (int e = 0; e < 4; ++e) {
      float vv = p[e];
      for (int off = 32; off; off >>= 1) vv += __shfl_down(vv, off);
      if (lane == 0) atomicAdd(&me_sum[e], vv);
    }
    unsigned long long lbm = (1ull << lane) - 1;
    for (int e = 0; e < 4; ++e) {
      // top-1 list + ce
      unsigned long long m0 = __ballot(i0 == e);
      int tot = __popcll(m0);
      int base = 0;
      if (lane == e && tot > 0) {
        base = atomicAdd(&cnt[e], tot);
        atomicAdd(&ce_sum[e], (float)tot);
      }
      base = __shfl(base, e);
      if (i0 == e) {
        int pos = base + __popcll(m0 & lbm);
        list[e * T_ + pos] = t;
        gatev[e * T_ + pos] = g0;
      }
      // top-2 list
      unsigned long long m1 = __ballot(i1 == e);
      int tot1 = __popcll(m1);
      int base1 = 0;
      if (lane == e && tot1 > 0) base1 = atomicAdd(&cnt[e], tot1);
      base1 = __shfl(base1, e);
      if (i1 == e) {
        int pos = base1 + __popcll(m1 & lbm);
        list[e * T_ + pos] = t;
        gatev[e * T_ + pos] = g1;
      }
    }
  }
}

__global__ void loss_offs_kernel(const float* __restrict__ me, const float* __restrict__ ce,
                                 const int* __restrict__ cnt, int* __restrict__ offs,
                                 float* __restrict__ out) {
  if (threadIdx.x == 0) {
    float l = 0.f;
    for (int e = 0; e < E_; ++e) l += (me[e] * (1.0f / T_)) * (ce[e] * (1.0f / T_));
    out[0] = (float)E_ * l;
    int o = 0;
    for (int e = 0; e < E_; ++e) { offs[e] = o; o += cnt[e]; }
  }
}

extern "C" void kernel_launch(void* const* d_in, const int* in_sizes, int n_in,
                              void* d_out, int out_size, void* d_ws, size_t ws_size,
                              hipStream_t stream) {
  const float* hid       = (const float*)d_in[0];
  const float* ln_in_g   = (const float*)d_in[1];
  const float* ln_in_b   = (const float*)d_in[2];
  const float* Wq        = (const float*)d_in[3];
  const float* Wkv       = (const float*)d_in[4];
  const float* Wo        = (const float*)d_in[5];
  const float* ln_attn_g = (const float*)d_in[6];
  const float* ln_attn_b = (const float*)d_in[7];
  const float* ln_post_g = (const float*)d_in[8];
  const float* ln_post_b = (const float*)d_in[9];
  const float* Wg        = (const float*)d_in[10];
  const float* W1        = (const float*)d_in[11];
  const float* b1        = (const float*)d_in[12];
  const float* W2        = (const float*)d_in[13];
  const float* b2        = (const float*)d_in[14];
  float* out = (float*)d_out;

  char* p = (char*)d_ws;
  size_t off = 0;
  auto alloc = [&](size_t bytes) -> void* {
    void* r = p + off; off += (bytes + 255) & ~(size_t)255; return r;
  };
  // Overlays (all alloc sizes are multiples of 256 -> regions are exactly contiguous):
  //   hmid_all (64MB, [8192 rows x DFF] bf16) = h+x+qh+ql+hbh+hbl   (all dead by MoE)
  //   attn_out (16MB f32) = qh+ql                                   (dead after attn)
  //   vTh/vTl (16MB) = hbh+hbl      (hbh/hbl dead after qkv_gemm; vT dead after attn)
  //   W1T (32MB) = kvh+kvl                                          (dead after attn)
  //   W2T (32MB) = avh..WoTl                                        (dead after Wo gemm)
  float* h        = (float*)alloc((size_t)T_ * D_ * 4);
  float* x        = (float*)alloc((size_t)T_ * D_ * 4);
  unsigned short* hmid_all = (unsigned short*)h;
  unsigned short* qh = (unsigned short*)alloc((size_t)T_ * 1024 * 2);
  unsigned short* ql = (unsigned short*)alloc((size_t)T_ * 1024 * 2);
  float* attn_out = (float*)qh;
  unsigned short* hbh = (unsigned short*)alloc((size_t)T_ * D_ * 2);
  unsigned short* hbl = (unsigned short*)alloc((size_t)T_ * D_ * 2);
  unsigned short* vTh = hbh;   // 8MB each: 2*16*64*2048 shorts
  unsigned short* vTl = hbl;
  unsigned short* xb  = (unsigned short*)alloc((size_t)T_ * D_ * 2);
  unsigned short* kvh = (unsigned short*)alloc((size_t)T_ * 2048 * 2);
  unsigned short* kvl = (unsigned short*)alloc((size_t)T_ * 2048 * 2);
  unsigned short* W1T = kvh;
  unsigned short* avh = (unsigned short*)alloc((size_t)T_ * 1024 * 2);
  unsigned short* avl = (unsigned short*)alloc((size_t)T_ * 1024 * 2);
  unsigned short* W2T = avh;
  unsigned short* WqTh  = (unsigned short*)alloc((size_t)1024 * 1024 * 2);
  unsigned short* WqTl  = (unsigned short*)alloc((size_t)1024 * 1024 * 2);
  unsigned short* WkvTh = (unsigned short*)alloc((size_t)2048 * 1024 * 2);
  unsigned short* WkvTl = (unsigned short*)alloc((size_t)2048 * 1024 * 2);
  unsigned short* WoTh  = (unsigned short*)alloc((size_t)1024 * 1024 * 2);
  unsigned short* WoTl  = (unsigned short*)alloc((size_t)1024 * 1024 * 2);
  void* ghdr = alloc(256);
  int* cnt = (int*)ghdr;
  float* me_sum = (float*)ghdr + 4;
  float* ce_sum = (float*)ghdr + 8;
  int* offs = (int*)ghdr + 12;
  int* list = (int*)alloc((size_t)E_ * T_ * 4);
  float* gatev = (float*)alloc((size_t)E_ * T_ * 4);

  hipMemsetAsync(ghdr, 0, 64, stream);

  dim3 tb(32, 8);
  transpose_cvt_split<<<dim3(32, 16), tb, 0, stream>>>(Wq, WqTh, WqTl, 1024, 1024);
  transpose_cvt_split<<<dim3(64, 16), tb, 0, stream>>>(Wkv, WkvTh, WkvTl, 1024, 2048);
  transpose_cvt_split<<<dim3(32, 16), tb, 0, stream>>>(Wo, WoTh, WoTl, 1024, 1024);

  ln_in_kernel<<<T_, 256, 0, stream>>>(hid, ln_in_g, ln_in_b, h, hbh, hbl);

  qkv_gemm<<<dim3(24, 32), 256, 0, stream>>>(hbh, hbl, WqTh, WqTl, WkvTh, WkvTl,
      qh, ql, kvh, kvl);

  // V -> head-major transposed layout (overwrites dead hbh/hbl)
  v_transpose<<<dim3(32, 32), 256, 0, stream>>>(kvh, kvl, vTh, vTl);

  attn_kernel<<<dim3(32, 32), 256, 0, stream>>>(qh, ql, kvh, kvl, vTh, vTl, avh, avl);

  gemm3f<64><<<dim3(8, 64), 256, 0, stream>>>(avh, avl, WoTh, WoTl, attn_out, 1024, 1024);

  ln_fused_kernel<<<T_, 256, 0, stream>>>(hid, h, attn_out, ln_attn_g, ln_attn_b,
      ln_post_g, ln_post_b, out, x, xb);

  gate_kernel<<<T_ / 64, 256, 0, stream>>>(x, Wg, cnt, me_sum, ce_sum, list, gatev);
  loss_offs_kernel<<<1, 64, 0, stream>>>(me_sum, ce_sum, cnt, offs, out + (size_t)T_ * D_);

  transpose_cvt<<<dim3(128, 16, 4), tb, 0, stream>>>(W1, W1T, 1024, 4096);
  transpose_cvt<<<dim3(32, 64, 4), tb, 0, stream>>>(W2, W2T, 4096, 1024);

  moe_up<<<dim3(32, 128), 256, 0, stream>>>(xb, W1T, hmid_all, DFF_, 1024,
      cnt, offs, list, b1);
  moe_down<<<dim3(8, 128, 2), 256, 0, stream>>>(hmid_all, W2T, D_, DFF_,
      cnt, offs, list, gatev, b2, out);
}

// Round 12
// 815.363 us; speedup vs baseline: 1.0628x; 1.0628x over previous
//
#include <hip/hip_runtime.h>
#include <cmath>

#define S_   2048
#define B_   2
#define D_   1024
#define H_   16
#define DH_  64
#define DFF_ 4096
#define E_   4
#define T_   4096
#define SCALE_ 0.125f

typedef __attribute__((ext_vector_type(8))) short short8;
typedef __attribute__((ext_vector_type(4))) float f32x4;
typedef __attribute__((ext_vector_type(4))) unsigned short u16x4;
typedef __attribute__((ext_vector_type(4))) unsigned int u32x4;

static __device__ __forceinline__ unsigned short f2bf(float f) {
  union { float f; unsigned int u; } v; v.f = f;
  unsigned int r = v.u + 0x7FFFu + ((v.u >> 16) & 1u);
  return (unsigned short)(r >> 16);
}

static __device__ __forceinline__ float bf2f(unsigned short u) {
  union { unsigned int u; float f; } v; v.u = (unsigned int)u << 16;
  return v.f;
}

static __device__ __forceinline__ f32x4 mfma16(short8 a, short8 b, f32x4 c) {
  return __builtin_amdgcn_mfma_f32_16x16x32_bf16(a, b, c, 0, 0, 0);
}

// async global->LDS: 16B per lane; LDS dest = wave-uniform base + lane*16.
static __device__ __forceinline__ void gll16(const unsigned short* g, unsigned short* l) {
  __builtin_amdgcn_global_load_lds(
      (const __attribute__((address_space(1))) void*)g,
      (__attribute__((address_space(3))) void*)l, 16, 0, 0);
}

// fast gelu: vv * e^(2u) / (e^(2u)+1), u = 0.797885*(v+0.044715 v^3); max err ~3e-4
static __device__ __forceinline__ float gelu_f(float vv) {
  float u = 0.7978845608f * (vv + 0.044715f * vv * vv * vv);
  u = fminf(fmaxf(u, -9.0f), 9.0f);
  float e2 = __expf(2.0f * u);
  return vv * e2 * (1.0f / (e2 + 1.0f));
}

// ---------------- transpose + fp32->bf16: out[c][r] = bf16(in[r][c]), z-batched ------
__global__ void transpose_cvt(const float* __restrict__ in, unsigned short* __restrict__ out,
                              int R, int C) {
  __shared__ float t[64][33];
  size_t boff = (size_t)blockIdx.z * R * C;
  in += boff; out += boff;
  int c0 = blockIdx.x * 32, r0 = blockIdx.y * 64;
  for (int i = threadIdx.y; i < 64; i += 8)
    t[i][threadIdx.x] = in[(size_t)(r0 + i) * C + c0 + threadIdx.x];
  __syncthreads();
  for (int i = threadIdx.y; i < 32; i += 8) {
    float v0 = t[2 * threadIdx.x][i], v1 = t[2 * threadIdx.x + 1][i];
    unsigned int pk = (unsigned int)f2bf(v0) | ((unsigned int)f2bf(v1) << 16);
    *(unsigned int*)(&out[(size_t)(c0 + i) * R + r0 + 2 * threadIdx.x]) = pk;
  }
}

__global__ void transpose_cvt_split(const float* __restrict__ in,
    unsigned short* __restrict__ outh, unsigned short* __restrict__ outl, int R, int C) {
  __shared__ float t[64][33];
  int c0 = blockIdx.x * 32, r0 = blockIdx.y * 64;
  for (int i = threadIdx.y; i < 64; i += 8)
    t[i][threadIdx.x] = in[(size_t)(r0 + i) * C + c0 + threadIdx.x];
  __syncthreads();
  for (int i = threadIdx.y; i < 32; i += 8) {
    float v0 = t[2 * threadIdx.x][i], v1 = t[2 * threadIdx.x + 1][i];
    unsigned short h0 = f2bf(v0), h1 = f2bf(v1);
    unsigned int hp = (unsigned int)h0 | ((unsigned int)h1 << 16);
    unsigned int lp = (unsigned int)f2bf(v0 - bf2f(h0)) |
                      ((unsigned int)f2bf(v1 - bf2f(h1)) << 16);
    size_t o = (size_t)(c0 + i) * R + r0 + 2 * threadIdx.x;
    *(unsigned int*)(&outh[o]) = hp;
    *(unsigned int*)(&outl[o]) = lp;
  }
}

// ---------------- V transpose: kv[(j*B+b)][n*128+64+d] -> vT[((b*16+n)*64+d)][j] ------
__global__ __launch_bounds__(256) void v_transpose(
    const unsigned short* __restrict__ kvh, const unsigned short* __restrict__ kvl,
    unsigned short* __restrict__ vTh, unsigned short* __restrict__ vTl) {
  __shared__ unsigned short th[64][72], tl[64][72];
  int j0 = blockIdx.x * 64;
  int bh = blockIdx.y;
  int b = bh & 1, n = bh >> 1;
  int tid = threadIdx.x;
  int jr = tid >> 3, dc = (tid & 7) * 8;
  for (int it = 0; it < 2; ++it) {
    int jj = it * 32 + jr;
    size_t src = ((size_t)((j0 + jj) * 2 + b)) * 2048 + n * 128 + 64 + dc;
    *(short8*)(&th[jj][dc]) = *(const short8*)(kvh + src);
    *(short8*)(&tl[jj][dc]) = *(const short8*)(kvl + src);
  }
  __syncthreads();
  int dr = tid >> 3, jc = (tid & 7) * 8;
  for (int it = 0; it < 2; ++it) {
    int d = it * 32 + dr;
    short8 oh, ol;
    for (int u = 0; u < 8; ++u) { oh[u] = th[jc + u][d]; ol[u] = tl[jc + u][d]; }
    size_t dst = ((size_t)((b * 16 + n) * 64 + d)) * 2048 + j0 + jc;
    *(short8*)(vTh + dst) = oh;
    *(short8*)(vTl + dst) = ol;
  }
}

// ---------------- block reduce (sum, sumsq) over 256 threads -------------------------
static __device__ __forceinline__ void block_reduce2(float& s, float& s2, float* sh) {
  __syncthreads();
  for (int off = 32; off; off >>= 1) { s += __shfl_down(s, off); s2 += __shfl_down(s2, off); }
  int w = threadIdx.x >> 6;
  if ((threadIdx.x & 63) == 0) { sh[w * 2] = s; sh[w * 2 + 1] = s2; }
  __syncthreads();
  s = sh[0] + sh[2] + sh[4] + sh[6];
  s2 = sh[1] + sh[3] + sh[5] + sh[7];
}

// ---------------- input layernorm: h (f32) + split bf16 ------------------------------
__global__ __launch_bounds__(256) void ln_in_kernel(const float* __restrict__ hid,
    const float* __restrict__ g, const float* __restrict__ b,
    float* __restrict__ h, unsigned short* __restrict__ hbh, unsigned short* __restrict__ hbl) {
  __shared__ float sh[8];
  int t = blockIdx.x, tid = threadIdx.x;
  size_t ro = (size_t)t * D_;
  f32x4 v = ((const f32x4*)(hid + ro))[tid];
  float s = v[0] + v[1] + v[2] + v[3];
  float s2 = v[0]*v[0] + v[1]*v[1] + v[2]*v[2] + v[3]*v[3];
  block_reduce2(s, s2, sh);
  float mean = s * (1.0f / D_);
  float var = s2 * (1.0f / D_) - mean * mean;
  float rstd = rsqrtf(var + 1e-6f);
  f32x4 gv = ((const f32x4*)g)[tid], bv = ((const f32x4*)b)[tid];
  f32x4 y; u16x4 yh, yl;
  for (int c = 0; c < 4; ++c) {
    float z = (v[c] - mean) * rstd * gv[c] + bv[c];
    y[c] = z; yh[c] = f2bf(z); yl[c] = f2bf(z - bf2f(yh[c]));
  }
  ((f32x4*)(h + ro))[tid] = y;
  ((u16x4*)(hbh + ro))[tid] = yh;
  ((u16x4*)(hbl + ro))[tid] = yl;
}

// ---------------- fused: attn-LN + residual + post-LN --------------------------------
__global__ __launch_bounds__(256) void ln_fused_kernel(
    const float* __restrict__ hid, const float* __restrict__ h, const float* __restrict__ ao,
    const float* __restrict__ ga, const float* __restrict__ ba,
    const float* __restrict__ gp, const float* __restrict__ bp,
    float* __restrict__ out, float* __restrict__ x, unsigned short* __restrict__ xb) {
  __shared__ float sh[8];
  int t = blockIdx.x, tid = threadIdx.x;
  size_t ro = (size_t)t * D_;
  f32x4 hv = ((const f32x4*)(h + ro))[tid];
  f32x4 av = ((const f32x4*)(ao + ro))[tid];
  f32x4 a = hv + av;
  float s = a[0] + a[1] + a[2] + a[3];
  float s2 = a[0]*a[0] + a[1]*a[1] + a[2]*a[2] + a[3]*a[3];
  block_reduce2(s, s2, sh);
  float mean = s * (1.0f / D_);
  float var = s2 * (1.0f / D_) - mean * mean;
  float rstd = rsqrtf(var + 1e-5f);
  f32x4 lg = ((const f32x4*)ga)[tid], lb = ((const f32x4*)ba)[tid];
  f32x4 hidv = ((const f32x4*)(hid + ro))[tid];
  f32x4 li;
  for (int c = 0; c < 4; ++c) li[c] = hidv[c] + (a[c] - mean) * rstd * lg[c] + lb[c];
  ((f32x4*)(out + ro))[tid] = li;
  float s3 = li[0] + li[1] + li[2] + li[3];
  float s4 = li[0]*li[0] + li[1]*li[1] + li[2]*li[2] + li[3]*li[3];
  block_reduce2(s3, s4, sh);
  float mean2 = s3 * (1.0f / D_);
  float var2 = s4 * (1.0f / D_) - mean2 * mean2;
  float rstd2 = rsqrtf(var2 + 1e-6f);
  f32x4 g2 = ((const f32x4*)gp)[tid], b2v = ((const f32x4*)bp)[tid];
  f32x4 xv; u16x4 xbv;
  for (int c = 0; c < 4; ++c) { float z = (li[c] - mean2) * rstd2 * g2[c] + b2v[c]; xv[c] = z; xbv[c] = f2bf(z); }
  ((f32x4*)(x + ro))[tid] = xv;
  ((u16x4*)(xb + ro))[tid] = xbv;
}

// ---------------- fused Q+KV split-bf16 GEMM, T3 pipeline + chunk swizzle ------------
// Q outputs are pre-scaled by SCALE (exact pow2) so attn skips per-score scaling.
__global__ __launch_bounds__(256) void qkv_gemm(
    const unsigned short* __restrict__ Ah, const unsigned short* __restrict__ Al,
    const unsigned short* __restrict__ WqTh, const unsigned short* __restrict__ WqTl,
    const unsigned short* __restrict__ WkvTh, const unsigned short* __restrict__ WkvTl,
    unsigned short* __restrict__ qh, unsigned short* __restrict__ ql,
    unsigned short* __restrict__ kvh, unsigned short* __restrict__ kvl) {
  const int K = 1024;
  int m0 = blockIdx.y * 128, n0g = blockIdx.x * 128;
  const unsigned short *Bh, *Bl;
  unsigned short *Ch, *Cl;
  int NC, n0;
  float cscale;
  if (n0g < 1024) { Bh = WqTh; Bl = WqTl; Ch = qh; Cl = ql; NC = 1024; n0 = n0g; cscale = SCALE_; }
  else { Bh = WkvTh; Bl = WkvTl; Ch = kvh; Cl = kvl; NC = 2048; n0 = n0g - 1024; cscale = 1.0f; }
  __shared__ unsigned short pool2[32768];
  unsigned short* buf[2] = { pool2, pool2 + 16384 };
  int tid = threadIdx.x;
  int lane = tid & 63, w = tid >> 6;
  int quad = lane >> 4, l15 = lane & 15;
  int wm = (w >> 1) * 64, wn = (w & 1) * 64;
  f32x4 acc[4][4];
  for (int i = 0; i < 4; ++i) for (int j = 0; j < 4; ++j) acc[i][j] = 0;
  int rs0 = w * 32 + (lane >> 2), rs1 = rs0 + 16;
  int sw = ((lane & 3) ^ ((lane >> 3) & 3)) * 8;   // pre-swizzled source chunk
  const unsigned short* gah0 = Ah + (size_t)(m0 + rs0) * K + sw;
  const unsigned short* gah1 = Ah + (size_t)(m0 + rs1) * K + sw;
  const unsigned short* gal0 = Al + (size_t)(m0 + rs0) * K + sw;
  const unsigned short* gal1 = Al + (size_t)(m0 + rs1) * K + sw;
  const unsigned short* gbh0 = Bh + (size_t)(n0 + rs0) * K + sw;
  const unsigned short* gbh1 = Bh + (size_t)(n0 + rs1) * K + sw;
  const unsigned short* gbl0 = Bl + (size_t)(n0 + rs0) * K + sw;
  const unsigned short* gbl1 = Bl + (size_t)(n0 + rs1) * K + sw;
  int so0 = (w * 2 + 0) * 512, so1 = (w * 2 + 1) * 512;
  int sq = (l15 >> 1) & 3;                          // read-side swizzle
  auto stage = [&](unsigned short* bb, int k) {
    gll16(gah0 + k, bb + so0);         gll16(gah1 + k, bb + so1);
    gll16(gal0 + k, bb + 4096 + so0);  gll16(gal1 + k, bb + 4096 + so1);
    gll16(gbh0 + k, bb + 8192 + so0);  gll16(gbh1 + k, bb + 8192 + so1);
    gll16(gbl0 + k, bb + 12288 + so0); gll16(gbl1 + k, bb + 12288 + so1);
  };
  auto compute = [&](const unsigned short* bb) {
    short8 afh[4], afl[4], bfh[4], bfl[4];
    for (int i = 0; i < 4; ++i) {
      int o = (wm + i * 16 + l15) * 32 + ((quad ^ sq) * 8);
      afh[i] = *(const short8*)(&bb[o]);
      afl[i] = *(const short8*)(&bb[4096 + o]);
    }
    for (int j = 0; j < 4; ++j) {
      int o = (wn + j * 16 + l15) * 32 + ((quad ^ sq) * 8);
      bfh[j] = *(const short8*)(&bb[8192 + o]);
      bfl[j] = *(const short8*)(&bb[12288 + o]);
    }
    for (int i = 0; i < 4; ++i)
      for (int j = 0; j < 4; ++j) {
        f32x4 a = acc[i][j];
        a = mfma16(afh[i], bfl[j], a);
        a = mfma16(afl[i], bfh[j], a);
        a = mfma16(afh[i], bfh[j], a);
        acc[i][j] = a;
      }
  };
  stage(buf[0], 0);
  __syncthreads();
  for (int k0 = 0; k0 < K; k0 += 64) {
    stage(buf[1], k0 + 32);
    compute(buf[0]);
    __syncthreads();
    if (k0 + 64 < K) stage(buf[0], k0 + 64);
    compute(buf[1]);
    __syncthreads();
  }
  // coalesced epilogue through LDS
  unsigned short* eph = &pool2[w * 1152];
  unsigned short* epl = &pool2[4608 + w * 1152];
  int row16 = lane >> 3, chunk = lane & 7;
  for (int i = 0; i < 4; ++i) {
    for (int j = 0; j < 4; ++j) {
      f32x4 a = acc[i][j];
      int lo = j * 16 + l15;
      for (int r = 0; r < 4; ++r) {
        float av = a[r] * cscale;
        unsigned short hb = f2bf(av);
        eph[(quad * 4 + r) * 72 + lo] = hb;
        epl[(quad * 4 + r) * 72 + lo] = f2bf(av - bf2f(hb));
      }
    }
    for (int it = 0; it < 2; ++it) {
      int rr = it * 8 + row16;
      size_t go = (size_t)(m0 + wm + i * 16 + rr) * NC + n0 + wn + chunk * 8;
      *(u32x4*)(&Ch[go]) = *(const u32x4*)(&eph[rr * 72 + chunk * 8]);
      *(u32x4*)(&Cl[go]) = *(const u32x4*)(&epl[rr * 72 + chunk * 8]);
    }
    __syncthreads();
  }
}

// ---------------- split-bf16 GEMM, MT x 128 tile, f32 output (Wo) --------------------
template<int MT>
__global__ __launch_bounds__(256) void gemm3f(
    const unsigned short* __restrict__ Ah, const unsigned short* __restrict__ Al,
    const unsigned short* __restrict__ Bh, const unsigned short* __restrict__ Bl,
    float* __restrict__ Cf, int N, int K) {
  int m0 = blockIdx.y * MT, n0 = blockIdx.x * 128;
  __shared__ unsigned short pool3[MT * 64 + 8192];
  unsigned short* Ash = pool3;
  unsigned short* Asl = pool3 + MT * 32;
  unsigned short* Bsh = pool3 + MT * 64;
  unsigned short* Bsl = pool3 + MT * 64 + 4096;
  int tid = threadIdx.x;
  int lane = tid & 63, w = tid >> 6;
  int quad = lane >> 4, l15 = lane & 15;
  int wm = (w >> 1) * (MT / 2), wn = (w & 1) * 64;
  constexpr int MI = MT / 32;
  f32x4 acc[MI][4];
  for (int i = 0; i < MI; ++i) for (int j = 0; j < 4; ++j) acc[i][j] = 0;
  constexpr int AI = MT / 64;  // A issues per wave
  int cofs = (lane & 3) * 8;
  const unsigned short* gah[AI]; const unsigned short* gal[AI];
  unsigned short *lAh[AI], *lAl[AI];
  for (int is = 0; is < AI; ++is) {
    int rs = w * (MT / 4) + is * 16 + (lane >> 2);
    gah[is] = Ah + (size_t)(m0 + rs) * K + cofs;
    gal[is] = Al + (size_t)(m0 + rs) * K + cofs;
    lAh[is] = &Ash[(w * AI + is) * 512];
    lAl[is] = &Asl[(w * AI + is) * 512];
  }
  int rsB0 = w * 32 + (lane >> 2), rsB1 = rsB0 + 16;
  const unsigned short* gbh0 = Bh + (size_t)(n0 + rsB0) * K + cofs;
  const unsigned short* gbh1 = Bh + (size_t)(n0 + rsB1) * K + cofs;
  const unsigned short* gbl0 = Bl + (size_t)(n0 + rsB0) * K + cofs;
  const unsigned short* gbl1 = Bl + (size_t)(n0 + rsB1) * K + cofs;
  unsigned short* lB0 = &Bsh[(w * 2 + 0) * 512];
  unsigned short* lB1 = &Bsh[(w * 2 + 1) * 512];
  unsigned short* lBl0 = &Bsl[(w * 2 + 0) * 512];
  unsigned short* lBl1 = &Bsl[(w * 2 + 1) * 512];
  for (int k0 = 0; k0 < K; k0 += 32) {
    __syncthreads();
    for (int is = 0; is < AI; ++is) { gll16(gah[is] + k0, lAh[is]); gll16(gal[is] + k0, lAl[is]); }
    gll16(gbh0 + k0, lB0); gll16(gbh1 + k0, lB1);
    gll16(gbl0 + k0, lBl0); gll16(gbl1 + k0, lBl1);
    __syncthreads();
    short8 afh[MI], afl[MI], bfh[4], bfl[4];
    for (int i = 0; i < MI; ++i) {
      int o = (wm + i * 16 + l15) * 32 + quad * 8;
      afh[i] = *(const short8*)(&Ash[o]);
      afl[i] = *(const short8*)(&Asl[o]);
    }
    for (int j = 0; j < 4; ++j) {
      int o = (wn + j * 16 + l15) * 32 + quad * 8;
      bfh[j] = *(const short8*)(&Bsh[o]);
      bfl[j] = *(const short8*)(&Bsl[o]);
    }
    for (int i = 0; i < MI; ++i)
      for (int j = 0; j < 4; ++j) {
        f32x4 a = acc[i][j];
        a = mfma16(afh[i], bfl[j], a);
        a = mfma16(afl[i], bfh[j], a);
        a = mfma16(afh[i], bfh[j], a);
        acc[i][j] = a;
      }
  }
  // coalesced f32 epilogue through LDS: per-wave 16x64 f32 slab (stride 68)
  __syncthreads();
  float* epf = (float*)(pool3 + w * 2176);
  for (int i = 0; i < MI; ++i) {
    for (int j = 0; j < 4; ++j) {
      f32x4 a = acc[i][j];
      for (int r = 0; r < 4; ++r) epf[(quad * 4 + r) * 68 + j * 16 + l15] = a[r];
    }
    for (int it = 0; it < 4; ++it) {
      int rr = (lane >> 4) + it * 4;
      int ch = lane & 15;
      *(f32x4*)(&Cf[(size_t)(m0 + wm + i * 16 + rr) * N + n0 + wn + ch * 4]) =
          *(const f32x4*)(&epf[rr * 68 + ch * 4]);
    }
    __syncthreads();
  }
}

// ---------------- MoE up: 3-buffer counted-vmcnt pipeline (T4), chunk swizzle --------
// Per phase: waitcnt vmcnt(4) [own tile-(i-2) loads done] -> s_barrier -> issue stage
// tile i+2 -> compute tile i. Loads get 2 phases to land; never drained to 0 in loop.
__global__ __launch_bounds__(256) void moe_up(
    const unsigned short* __restrict__ A, const unsigned short* __restrict__ W1T,
    unsigned short* __restrict__ hmid, int N, int K,
    const int* __restrict__ cnt, const int* __restrict__ offs,
    const int* __restrict__ list, const float* __restrict__ b1) {
  int e = blockIdx.y >> 5, mt = blockIdx.y & 31;
  int M = cnt[e];
  int m0 = mt * 128, n0 = blockIdx.x * 128;
  if (M == 0 || m0 >= M) return;
  const unsigned short* Bt = W1T + (size_t)e * DFF_ * D_;
  const int* liste = list + e * T_;
  const float* bias = b1 + (size_t)e * DFF_;
  size_t obase = (size_t)offs[e];
  __shared__ unsigned short pool[24576];   // 48 KB: 3 x (A 4096 + B 4096 shorts)
  unsigned short* bufA[3] = { pool,         pool + 8192,  pool + 16384 };
  unsigned short* bufB[3] = { pool + 4096,  pool + 12288, pool + 20480 };
  int tid = threadIdx.x;
  int lane = tid & 63, w = tid >> 6;
  int quad = lane >> 4, l15 = lane & 15;
  int wm = (w >> 1) * 64, wn = (w & 1) * 64;
  f32x4 acc[4][4];
  for (int i = 0; i < 4; ++i) for (int j = 0; j < 4; ++j) acc[i][j] = 0;
  int rs0 = w * 32 + (lane >> 2), rs1 = rs0 + 16;
  int sw = ((lane & 3) ^ ((lane >> 3) & 3)) * 8;    // pre-swizzled source chunk
  const unsigned short* ga0 = A + (size_t)liste[min(m0 + rs0, M - 1)] * K + sw;
  const unsigned short* ga1 = A + (size_t)liste[min(m0 + rs1, M - 1)] * K + sw;
  const unsigned short* gb0 = Bt + (size_t)(n0 + rs0) * K + sw;
  const unsigned short* gb1 = Bt + (size_t)(n0 + rs1) * K + sw;
  int so0 = (w * 2 + 0) * 512, so1 = (w * 2 + 1) * 512;
  int sq = (l15 >> 1) & 3;                           // read-side swizzle
  auto stage = [&](unsigned short* Ab, unsigned short* Bb, int k) {
    gll16(ga0 + k, Ab + so0); gll16(ga1 + k, Ab + so1);
    gll16(gb0 + k, Bb + so0); gll16(gb1 + k, Bb + so1);
  };
  auto compute = [&](const unsigned short* Ab, const unsigned short* Bb) {
    short8 af[4], bfr[4];
    for (int i = 0; i < 4; ++i)
      af[i] = *(const short8*)(&Ab[(wm + i * 16 + l15) * 32 + (quad ^ sq) * 8]);
    for (int j = 0; j < 4; ++j)
      bfr[j] = *(const short8*)(&Bb[(wn + j * 16 + l15) * 32 + (quad ^ sq) * 8]);
    for (int i = 0; i < 4; ++i)
      for (int j = 0; j < 4; ++j)
        acc[i][j] = mfma16(af[i], bfr[j], acc[i][j]);
  };
  // prologue: tiles 0 and 1 in flight (4 loads each per wave)
  stage(bufA[0], bufB[0], 0);
  stage(bufA[1], bufB[1], 32);
  unsigned short *a0 = bufA[0], *b0 = bufB[0];
  unsigned short *a1 = bufA[1], *b1v = bufB[1];
  unsigned short *a2 = bufA[2], *b2v = bufB[2];
  for (int k0 = 0; k0 < K; k0 += 32) {
    if (k0 + 32 < K) asm volatile("s_waitcnt vmcnt(4)" ::: "memory");
    else             asm volatile("s_waitcnt vmcnt(0)" ::: "memory");
    __builtin_amdgcn_s_barrier();
    asm volatile("" ::: "memory");
    if (k0 + 64 < K) stage(a2, b2v, k0 + 64);
    compute(a0, b0);
    unsigned short* t;
    t = a0; a0 = a1; a1 = a2; a2 = t;
    t = b0; b0 = b1v; b1v = b2v; b2v = t;
  }
  __syncthreads();
  // coalesced epilogue through LDS: per-wave 16x64 slab, stride 72
  unsigned short* ep = &pool[w * 1152];
  int row16 = lane >> 3, chunk = lane & 7;
  for (int i = 0; i < 4; ++i) {
    for (int j = 0; j < 4; ++j) {
      f32x4 a = acc[i][j];
      int colg = n0 + wn + j * 16 + l15;
      float bv = bias[colg];
      for (int r = 0; r < 4; ++r)
        ep[(quad * 4 + r) * 72 + j * 16 + l15] = f2bf(gelu_f(a[r] + bv));
    }
    for (int it = 0; it < 2; ++it) {
      int rr = it * 8 + row16;
      int rowg = m0 + wm + i * 16 + rr;
      if (rowg < M)
        *(u32x4*)(&hmid[(obase + rowg) * DFF_ + n0 + wn + chunk * 8]) =
            *(const u32x4*)(&ep[rr * 72 + chunk * 8]);
    }
  }
}

// ---------------- MoE down: 3-buffer counted-vmcnt pipeline (T4), chunk swizzle ------
// grid (D/128, E*32); atomic accum epilogue.
__global__ __launch_bounds__(256) void moe_down(
    const unsigned short* __restrict__ hmid, const unsigned short* __restrict__ W2T,
    int N, int K,
    const int* __restrict__ cnt, const int* __restrict__ offs,
    const int* __restrict__ list, const float* __restrict__ gatev,
    const float* __restrict__ b2, float* __restrict__ accum) {
  int e = blockIdx.y >> 5, mt = blockIdx.y & 31;
  int M = cnt[e];
  int m0 = mt * 128, n0 = blockIdx.x * 128;
  if (M == 0 || m0 >= M) return;
  const unsigned short* A = hmid + (size_t)offs[e] * DFF_;
  const unsigned short* Bt = W2T + (size_t)e * D_ * DFF_;
  const int* liste = list + e * T_;
  const float* gv = gatev + e * T_;
  const float* bias = b2 + (size_t)e * D_;
  __shared__ unsigned short pool[24576];
  unsigned short* bufA[3] = { pool,         pool + 8192,  pool + 16384 };
  unsigned short* bufB[3] = { pool + 4096,  pool + 12288, pool + 20480 };
  int tid = threadIdx.x;
  int lane = tid & 63, w = tid >> 6;
  int quad = lane >> 4, l15 = lane & 15;
  int wm = (w >> 1) * 64, wn = (w & 1) * 64;
  f32x4 acc[4][4];
  for (int i = 0; i < 4; ++i) for (int j = 0; j < 4; ++j) acc[i][j] = 0;
  int rs0 = w * 32 + (lane >> 2), rs1 = rs0 + 16;
  int sw = ((lane & 3) ^ ((lane >> 3) & 3)) * 8;
  const unsigned short* ga0 = A + (size_t)min(m0 + rs0, M - 1) * K + sw;
  const unsigned short* ga1 = A + (size_t)min(m0 + rs1, M - 1) * K + sw;
  const unsigned short* gb0 = Bt + (size_t)(n0 + rs0) * K + sw;
  const unsigned short* gb1 = Bt + (size_t)(n0 + rs1) * K + sw;
  int so0 = (w * 2 + 0) * 512, so1 = (w * 2 + 1) * 512;
  int sq = (l15 >> 1) & 3;
  auto stage = [&](unsigned short* Ab, unsigned short* Bb, int k) {
    gll16(ga0 + k, Ab + so0); gll16(ga1 + k, Ab + so1);
    gll16(gb0 + k, Bb + so0); gll16(gb1 + k, Bb + so1);
  };
  auto compute = [&](const unsigned short* Ab, const unsigned short* Bb) {
    short8 af[4], bfr[4];
    for (int i = 0; i < 4; ++i)
      af[i] = *(const short8*)(&Ab[(wm + i * 16 + l15) * 32 + (quad ^ sq) * 8]);
    for (int j = 0; j < 4; ++j)
      bfr[j] = *(const short8*)(&Bb[(wn + j * 16 + l15) * 32 + (quad ^ sq) * 8]);
    for (int i = 0; i < 4; ++i)
      for (int j = 0; j < 4; ++j)
        acc[i][j] = mfma16(af[i], bfr[j], acc[i][j]);
  };
  stage(bufA[0], bufB[0], 0);
  stage(bufA[1], bufB[1], 32);
  unsigned short *a0 = bufA[0], *b0 = bufB[0];
  unsigned short *a1 = bufA[1], *b1v = bufB[1];
  unsigned short *a2 = bufA[2], *b2v = bufB[2];
  for (int k0 = 0; k0 < K; k0 += 32) {
    if (k0 + 32 < K) asm volatile("s_waitcnt vmcnt(4)" ::: "memory");
    else             asm volatile("s_waitcnt vmcnt(0)" ::: "memory");
    __builtin_amdgcn_s_barrier();
    asm volatile("" ::: "memory");
    if (k0 + 64 < K) stage(a2, b2v, k0 + 64);
    compute(a0, b0);
    unsigned short* t;
    t = a0; a0 = a1; a1 = a2; a2 = t;
    t = b0; b0 = b1v; b1v = b2v; b2v = t;
  }
  __syncthreads();
  for (int i = 0; i < 4; ++i) for (int j = 0; j < 4; ++j) {
    int row = m0 + wm + i * 16 + quad * 4;
    int col = n0 + wn + j * 16 + l15;
    f32x4 a = acc[i][j];
    float bv = bias[col];
    for (int r = 0; r < 4; ++r) if (row + r < M) {
      int tt = liste[row + r];
      float gg = gv[row + r];
      atomicAdd(&accum[(size_t)tt * D_ + col], gg * (a[r] + bv));
    }
  }
}

// ---------------- flash attention: shared LDS K+V, T3 pipeline, lean softmax ---------
// Q pre-scaled by SCALE in qkv_gemm. Defer-max (THR=8, exact when skipped) +
// per-lane partial l (reduced once at end).
__global__ __launch_bounds__(256, 2) void attn_kernel(
    const unsigned short* __restrict__ qh, const unsigned short* __restrict__ ql,
    const unsigned short* __restrict__ kvh, const unsigned short* __restrict__ kvl,
    const unsigned short* __restrict__ vTh, const unsigned short* __restrict__ vTl,
    unsigned short* __restrict__ avh, unsigned short* __restrict__ avl) {
  int bh = blockIdx.x;     // x = bh so all q-tiles of one (b,head) share an XCD (bh%8)
  int itile = blockIdx.y;
  int b = bh & 1, n = bh >> 1;
  __shared__ unsigned short Kh[2][4096], Kl[2][4096], Vh[2][4096], Vl[2][4096];
  __shared__ unsigned short Ps[4][1152];
  int tid = threadIdx.x;
  int w = tid >> 6, lane = tid & 63, quad = lane >> 4, l15 = lane & 15;
  int i_base = itile * 64 + w * 16;
  short8 qfh[2], qfl[2];
  {
    size_t qo = ((size_t)((i_base + l15) * B_ + b)) * 1024 + n * 64;
    qfh[0] = *(const short8*)(qh + qo + quad * 8);
    qfh[1] = *(const short8*)(qh + qo + 32 + quad * 8);
    qfl[0] = *(const short8*)(ql + qo + quad * 8);
    qfl[1] = *(const short8*)(ql + qo + 32 + quad * 8);
  }
  float m_i[4], lp[4];
  f32x4 o[4];
  for (int r = 0; r < 4; ++r) { m_i[r] = -1e30f; lp[r] = 0.0f; }
  for (int d = 0; d < 4; ++d) o[d] = 0;
  // staging: thread t covers tile rows jk and jk+32 with swizzled chunk ck
  int jk = tid >> 3;
  int ck = (tid & 7) ^ (jk & 7);
  size_t kS = ((size_t)(jk * 2 + b)) * 2048 + (size_t)n * 128 + ck * 8;   // +jt*262144; +131072 upper
  size_t vS = ((size_t)((b * 16 + n) * 64 + jk)) * 2048 + ck * 8;         // +jt*64; +65536 upper
  int ldst = tid * 8;
  unsigned short* psw = &Ps[w][0];
  // prologue: stage tile 0 into buffer 0
  gll16(kvh + kS, &Kh[0][ldst]);           gll16(kvh + kS + 131072, &Kh[0][2048 + ldst]);
  gll16(kvl + kS, &Kl[0][ldst]);           gll16(kvl + kS + 131072, &Kl[0][2048 + ldst]);
  gll16(vTh + vS, &Vh[0][ldst]);           gll16(vTh + vS + 65536, &Vh[0][2048 + ldst]);
  gll16(vTl + vS, &Vl[0][ldst]);           gll16(vTl + vS + 65536, &Vl[0][2048 + ldst]);
  __syncthreads();
  for (int jt = 0; jt < 32; ++jt) {
    int cur = jt & 1;
    if (jt < 31) {   // stage next tile into other buffer; lands by loop-end barrier
      int nb = cur ^ 1;
      size_t ks2 = kS + (size_t)(jt + 1) * 262144;
      size_t vs2 = vS + (size_t)(jt + 1) * 64;
      gll16(kvh + ks2, &Kh[nb][ldst]);     gll16(kvh + ks2 + 131072, &Kh[nb][2048 + ldst]);
      gll16(kvl + ks2, &Kl[nb][ldst]);     gll16(kvl + ks2 + 131072, &Kl[nb][2048 + ldst]);
      gll16(vTh + vs2, &Vh[nb][ldst]);     gll16(vTh + vs2 + 65536, &Vh[nb][2048 + ldst]);
      gll16(vTl + vs2, &Vl[nb][ldst]);     gll16(vTl + vs2 + 65536, &Vl[nb][2048 + ldst]);
    }
    // QK^T from swizzled LDS (scores already scaled: Q pre-scaled by SCALE)
    f32x4 sac[4];
    __builtin_amdgcn_s_setprio(1);
    for (int t4 = 0; t4 < 4; ++t4) {
      int j = t4 * 16 + l15;
      int base = j * 64;
      int c0 = (quad ^ (j & 7)) << 3;
      int c1 = ((quad | 4) ^ (j & 7)) << 3;
      short8 kh0 = *(const short8*)(&Kh[cur][base + c0]);
      short8 kh1 = *(const short8*)(&Kh[cur][base + c1]);
      short8 kl0 = *(const short8*)(&Kl[cur][base + c0]);
      short8 kl1 = *(const short8*)(&Kl[cur][base + c1]);
      f32x4 a = 0;
      a = mfma16(qfh[0], kl0, a);
      a = mfma16(qfh[1], kl1, a);
      a = mfma16(qfl[0], kh0, a);
      a = mfma16(qfl[1], kh1, a);
      a = mfma16(qfh[0], kh0, a);
      a = mfma16(qfh[1], kh1, a);
      sac[t4] = a;
    }
    __builtin_amdgcn_s_setprio(0);
    // lean online softmax: defer-max (THR=8) + per-lane partial l
    float m1[4];
    for (int r = 0; r < 4; ++r) {
      float v = fmaxf(fmaxf(sac[0][r], sac[1][r]), fmaxf(sac[2][r], sac[3][r]));
      for (int off = 1; off < 16; off <<= 1) v = fmaxf(v, __shfl_xor(v, off, 16));
      m1[r] = v;
    }
    float p[4][4];
    bool ok = (m1[0] <= m_i[0] + 8.f) && (m1[1] <= m_i[1] + 8.f) &&
              (m1[2] <= m_i[2] + 8.f) && (m1[3] <= m_i[3] + 8.f);
    if (__all(ok)) {
      for (int r = 0; r < 4; ++r) {
        float rs = 0.f;
        for (int t4 = 0; t4 < 4; ++t4) {
          float pp = __expf(sac[t4][r] - m_i[r]);
          p[t4][r] = pp; rs += pp;
        }
        lp[r] += rs;
      }
    } else {
      float alpha[4];
      for (int r = 0; r < 4; ++r) {
        float mnew = fmaxf(m_i[r], m1[r]);
        alpha[r] = __expf(m_i[r] - mnew);
        m_i[r] = mnew;
        float rs = 0.f;
        for (int t4 = 0; t4 < 4; ++t4) {
          float pp = __expf(sac[t4][r] - mnew);
          p[t4][r] = pp; rs += pp;
        }
        lp[r] = lp[r] * alpha[r] + rs;
      }
      for (int d = 0; d < 4; ++d) for (int r = 0; r < 4; ++r) o[d][r] *= alpha[r];
    }
    // restage P (high only) into wave-private slab; compiler lgkmcnt orders PV reads
    for (int t4 = 0; t4 < 4; ++t4) for (int r = 0; r < 4; ++r)
      psw[(quad * 4 + r) * 72 + t4 * 16 + l15] = f2bf(p[t4][r]);
    // PV from swizzled LDS V
    __builtin_amdgcn_s_setprio(1);
    for (int dblk = 0; dblk < 4; ++dblk) {
      f32x4 a = o[dblk];
      int d = dblk * 16 + l15;
      int vb = d * 64;
      for (int ks = 0; ks < 2; ++ks) {
        short8 pfh = *(const short8*)(&psw[l15 * 72 + ks * 32 + quad * 8]);
        int ch = ((ks * 4 + quad) ^ (d & 7)) << 3;
        short8 vfh = *(const short8*)(&Vh[cur][vb + ch]);
        short8 vfl = *(const short8*)(&Vl[cur][vb + ch]);
        a = mfma16(pfh, vfl, a);
        a = mfma16(pfh, vfh, a);
      }
      o[dblk] = a;
    }
    __builtin_amdgcn_s_setprio(0);
    __syncthreads();   // drains vmcnt: next tile staged; buffers safe to swap
  }
  // final l reduce (once) + coalesced epilogue through wave-private slab
  float l_i[4];
  for (int r = 0; r < 4; ++r) {
    float v = lp[r];
    for (int off = 1; off < 16; off <<= 1) v += __shfl_xor(v, off, 16);
    l_i[r] = v;
  }
  {
    int row16 = lane >> 3, chunk = lane & 7;
    for (int d = 0; d < 4; ++d) for (int r = 0; r < 4; ++r) {
      float val = o[d][r] / l_i[r];
      psw[(quad * 4 + r) * 72 + d * 16 + l15] = f2bf(val);
    }
    for (int it = 0; it < 2; ++it) {
      int rr = it * 8 + row16;
      size_t go = ((size_t)((i_base + rr) * B_ + b)) * 1024 + n * 64 + chunk * 8;
      *(u32x4*)(&avh[go]) = *(const u32x4*)(&psw[rr * 72 + chunk * 8]);
    }
    __syncthreads();
    for (int d = 0; d < 4; ++d) for (int r = 0; r < 4; ++r) {
      float val = o[d][r] / l_i[r];
      unsigned short hb = f2bf(val);
      psw[(quad * 4 + r) * 72 + d * 16 + l15] = f2bf(val - bf2f(hb));
    }
    for (int it = 0; it < 2; ++it) {
      int rr = it * 8 + row16;
      size_t go = ((size_t)((i_base + rr) * B_ + b)) * 1024 + n * 64 + chunk * 8;
      *(u32x4*)(&avl[go]) = *(const u32x4*)(&psw[rr * 72 + chunk * 8]);
    }
  }
}

// ---------------- gating v2: 64 tokens/block, ballot-based list build ----------------
__global__ __launch_bounds__(256) void gate_kernel(const float* __restrict__ x,
    const float* __restrict__ Wg, int* __restrict__ cnt,
    float* __restrict__ me_sum, float* __restrict__ ce_sum,
    int* __restrict__ list, float* __restrict__ gatev) {
  __shared__ float sl[64][4];
  int w = threadIdx.x >> 6, lane = threadIdx.x & 63;
  int tbase = blockIdx.x * 64;
  // Phase A: logits for 64 tokens (16 per wave, full-wave dot each)
  for (int k = 0; k < 16; ++k) {
    int t = tbase + w * 16 + k;
    f32x4 acc = 0;
    const float* xr = x + (size_t)t * D_;
    for (int j = 0; j < 16; ++j) {
      int d = j * 64 + lane;
      float xd = xr[d];
      f32x4 wg = ((const f32x4*)Wg)[d];
      acc += xd * wg;
    }
    for (int c = 0; c < 4; ++c) {
      float vv = acc[c];
      for (int off = 32; off; off >>= 1) vv += __shfl_down(vv, off);
      if (lane == 0) sl[w * 16 + k][c] = vv;
    }
  }
  __syncthreads();
  // Phase B: wave 0 only; one token per lane
  if (w == 0) {
    int t = tbase + lane;
    float p[4];
    float mx = fmaxf(fmaxf(sl[lane][0], sl[lane][1]), fmaxf(sl[lane][2], sl[lane][3]));
    float sum = 0.f;
    for (int e = 0; e < 4; ++e) { p[e] = expf(sl[lane][e] - mx); sum += p[e]; }
    float inv = 1.0f / sum;
    for (int e = 0; e < 4; ++e) p[e] *= inv;
    int i0 = 0;
    for (int e = 1; e < 4; ++e) if (p[e] > p[i0]) i0 = e;
    int i1 = (i0 == 0) ? 1 : 0;
    for (int e = 0; e < 4; ++e) if (e != i0 && p[e] > p[i1]) i1 = e;
    float g0 = p[i0] / (p[i0] + p[i1]);
    float g1 = p[i1] / (p[i0] + p[i1]);
    // me_sum: block-reduce probs, 4 atomics
    for (int e = 0; e < 4; ++e) {
      float vv = p[e];
      for (int off = 32; off; off >>= 1) vv += __shfl_down(vv, off);
      if (lane == 0) atomicAdd(&me_sum[e], vv);
    }
    unsigned long long lbm = (1ull << lane) - 1;
    for (int e = 0; e < 4; ++e) {
      // top-1 list + ce
      unsigned long long m0 = __ballot(i0 == e);
      int tot = __popcll(m0);
      int base = 0;
      if (lane == e && tot > 0) {
        base = atomicAdd(&cnt[e], tot);
        atomicAdd(&ce_sum[e], (float)tot);
      }
      base = __shfl(base, e);
      if (i0 == e) {
        int pos = base + __popcll(m0 & lbm);
        list[e * T_ + pos] = t;
        gatev[e * T_ + pos] = g0;
      }
      // top-2 list
      unsigned long long m1 = __ballot(i1 == e);
      int tot1 = __popcll(m1);
      int base1 = 0;
      if (lane == e && tot1 > 0) base1 = atomicAdd(&cnt[e], tot1);
      base1 = __shfl(base1, e);
      if (i1 == e) {
        int pos = base1 + __popcll(m1 & lbm);
        list[e * T_ + pos] = t;
        gatev[e * T_ + pos] = g1;
      }
    }
  }
}

__global__ void loss_offs_kernel(const float* __restrict__ me, const float* __restrict__ ce,
                                 const int* __restrict__ cnt, int* __restrict__ offs,
                                 float* __restrict__ out) {
  if (threadIdx.x == 0) {
    float l = 0.f;
    for (int e = 0; e < E_; ++e) l += (me[e] * (1.0f / T_)) * (ce[e] * (1.0f / T_));
    out[0] = (float)E_ * l;
    int o = 0;
    for (int e = 0; e < E_; ++e) { offs[e] = o; o += cnt[e]; }
  }
}

extern "C" void kernel_launch(void* const* d_in, const int* in_sizes, int n_in,
                              void* d_out, int out_size, void* d_ws, size_t ws_size,
                              hipStream_t stream) {
  const float* hid       = (const float*)d_in[0];
  const float* ln_in_g   = (const float*)d_in[1];
  const float* ln_in_b   = (const float*)d_in[2];
  const float* Wq        = (const float*)d_in[3];
  const float* Wkv       = (const float*)d_in[4];
  const float* Wo        = (const float*)d_in[5];
  const float* ln_attn_g = (const float*)d_in[6];
  const float* ln_attn_b = (const float*)d_in[7];
  const float* ln_post_g = (const float*)d_in[8];
  const float* ln_post_b = (const float*)d_in[9];
  const float* Wg        = (const float*)d_in[10];
  const float* W1        = (const float*)d_in[11];
  const float* b1        = (const float*)d_in[12];
  const float* W2        = (const float*)d_in[13];
  const float* b2        = (const float*)d_in[14];
  float* out = (float*)d_out;

  char* p = (char*)d_ws;
  size_t off = 0;
  auto alloc = [&](size_t bytes) -> void* {
    void* r = p + off; off += (bytes + 255) & ~(size_t)255; return r;
  };
  // Overlays (all alloc sizes are multiples of 256 -> regions are exactly contiguous):
  //   hmid_all (64MB, [8192 rows x DFF] bf16) = h+x+qh+ql+hbh+hbl   (all dead by MoE)
  //   attn_out (16MB f32) = qh+ql                                   (dead after attn)
  //   vTh/vTl (16MB) = hbh+hbl      (hbh/hbl dead after qkv_gemm; vT dead after attn)
  //   W1T (32MB) = kvh+kvl                                          (dead after attn)
  //   W2T (32MB) = avh..WoTl                                        (dead after Wo gemm)
  float* h        = (float*)alloc((size_t)T_ * D_ * 4);
  float* x        = (float*)alloc((size_t)T_ * D_ * 4);
  unsigned short* hmid_all = (unsigned short*)h;
  unsigned short* qh = (unsigned short*)alloc((size_t)T_ * 1024 * 2);
  unsigned short* ql = (unsigned short*)alloc((size_t)T_ * 1024 * 2);
  float* attn_out = (float*)qh;
  unsigned short* hbh = (unsigned short*)alloc((size_t)T_ * D_ * 2);
  unsigned short* hbl = (unsigned short*)alloc((size_t)T_ * D_ * 2);
  unsigned short* vTh = hbh;   // 8MB each: 2*16*64*2048 shorts
  unsigned short* vTl = hbl;
  unsigned short* xb  = (unsigned short*)alloc((size_t)T_ * D_ * 2);
  unsigned short* kvh = (unsigned short*)alloc((size_t)T_ * 2048 * 2);
  unsigned short* kvl = (unsigned short*)alloc((size_t)T_ * 2048 * 2);
  unsigned short* W1T = kvh;
  unsigned short* avh = (unsigned short*)alloc((size_t)T_ * 1024 * 2);
  unsigned short* avl = (unsigned short*)alloc((size_t)T_ * 1024 * 2);
  unsigned short* W2T = avh;
  unsigned short* WqTh  = (unsigned short*)alloc((size_t)1024 * 1024 * 2);
  unsigned short* WqTl  = (unsigned short*)alloc((size_t)1024 * 1024 * 2);
  unsigned short* WkvTh = (unsigned short*)alloc((size_t)2048 * 1024 * 2);
  unsigned short* WkvTl = (unsigned short*)alloc((size_t)2048 * 1024 * 2);
  unsigned short* WoTh  = (unsigned short*)alloc((size_t)1024 * 1024 * 2);
  unsigned short* WoTl  = (unsigned short*)alloc((size_t)1024 * 1024 * 2);
  void* ghdr = alloc(256);
  int* cnt = (int*)ghdr;
  float* me_sum = (float*)ghdr + 4;
  float* ce_sum = (float*)ghdr + 8;
  int* offs = (int*)ghdr + 12;
  int* list = (int*)alloc((size_t)E_ * T_ * 4);
  float* gatev = (float*)alloc((size_t)E_ * T_ * 4);

  hipMemsetAsync(ghdr, 0, 64, stream);

  dim3 tb(32, 8);
  transpose_cvt_split<<<dim3(32, 16), tb, 0, stream>>>(Wq, WqTh, WqTl, 1024, 1024);
  transpose_cvt_split<<<dim3(64, 16), tb, 0, stream>>>(Wkv, WkvTh, WkvTl, 1024, 2048);
  transpose_cvt_split<<<dim3(32, 16), tb, 0, stream>>>(Wo, WoTh, WoTl, 1024, 1024);

  ln_in_kernel<<<T_, 256, 0, stream>>>(hid, ln_in_g, ln_in_b, h, hbh, hbl);

  qkv_gemm<<<dim3(24, 32), 256, 0, stream>>>(hbh, hbl, WqTh, WqTl, WkvTh, WkvTl,
      qh, ql, kvh, kvl);

  // V -> head-major transposed layout (overwrites dead hbh/hbl)
  v_transpose<<<dim3(32, 32), 256, 0, stream>>>(kvh, kvl, vTh, vTl);

  attn_kernel<<<dim3(32, 32), 256, 0, stream>>>(qh, ql, kvh, kvl, vTh, vTl, avh, avl);

  gemm3f<64><<<dim3(8, 64), 256, 0, stream>>>(avh, avl, WoTh, WoTl, attn_out, 1024, 1024);

  ln_fused_kernel<<<T_, 256, 0, stream>>>(hid, h, attn_out, ln_attn_g, ln_attn_b,
      ln_post_g, ln_post_b, out, x, xb);

  gate_kernel<<<T_ / 64, 256, 0, stream>>>(x, Wg, cnt, me_sum, ce_sum, list, gatev);
  loss_offs_kernel<<<1, 64, 0, stream>>>(me_sum, ce_sum, cnt, offs, out + (size_t)T_ * D_);

  transpose_cvt<<<dim3(128, 16, 4), tb, 0, stream>>>(W1, W1T, 1024, 4096);
  transpose_cvt<<<dim3(32, 64, 4), tb, 0, stream>>>(W2, W2T, 4096, 1024);

  moe_up<<<dim3(32, 128), 256, 0, stream>>>(xb, W1T, hmid_all, DFF_, 1024,
      cnt, offs, list, b1);
  moe_down<<<dim3(8, 128), 256, 0, stream>>>(hmid_all, W2T, D_, DFF_,
      cnt, offs, list, gatev, b2, out);
}